// Round 1
// baseline (358.331 us; speedup 1.0000x reference)
//
#include <hip/hip_runtime.h>
#include <hip/hip_bf16.h>

#define D 128
#define NG 128
#define PROWS 128

typedef __attribute__((ext_vector_type(8))) short bf16x8;
typedef __attribute__((ext_vector_type(4))) float f32x4;

__device__ inline unsigned short f2bf(float f) {
  union { float f; unsigned u; } c; c.f = f;
  unsigned u = c.u;
  return (unsigned short)((u + 0x7FFFu + ((u >> 16) & 1u)) >> 16);  // RNE
}
__device__ inline float bf2f(unsigned short b) {
  union { unsigned u; float f; } c; c.u = ((unsigned)b) << 16;
  return c.f;
}

// Transpose + bf16-convert weights: Wt[l][n][k] = bf16(W[l][k][n]).
// Also zeroes deg[] (folded to save a launch).
__global__ void prep_w(const float* __restrict__ W1, const float* __restrict__ W2,
                       unsigned short* __restrict__ Wt1, unsigned short* __restrict__ Wt2,
                       int* __restrict__ deg, int N) {
  int t = blockIdx.x * 256 + threadIdx.x;
  if (t < N) deg[t] = 0;
  if (t >= 3 * 128 * 128) return;
  int l = t >> 14, k = (t >> 7) & 127, n = t & 127;
  int o = (l << 14) + (n << 7) + k;
  Wt1[o] = f2bf(W1[t]);
  Wt2[o] = f2bf(W2[t]);
}

// ---------------- CSR build ------------------------------------------------

__global__ void hist_deg(const int* __restrict__ dst, int* __restrict__ deg, int E) {
  int e = blockIdx.x * 256 + threadIdx.x;
  if (e < E) atomicAdd(deg + dst[e], 1);
}

__global__ __launch_bounds__(256) void scan1(const int* __restrict__ deg,
    int* __restrict__ rowptr, int* __restrict__ bsum, int n) {
  __shared__ int sh[256];
  int tid = threadIdx.x;
  int idx = blockIdx.x * 1024 + tid * 4;
  int v[4], tsum = 0;
#pragma unroll
  for (int j = 0; j < 4; ++j) { v[j] = (idx + j < n) ? deg[idx + j] : 0; tsum += v[j]; }
  sh[tid] = tsum;
  __syncthreads();
  for (int off = 1; off < 256; off <<= 1) {
    int x = (tid >= off) ? sh[tid - off] : 0;
    __syncthreads();
    sh[tid] += x;
    __syncthreads();
  }
  if (tid == 255) bsum[blockIdx.x] = sh[255];
  int run = sh[tid] - tsum;
#pragma unroll
  for (int j = 0; j < 4; ++j) { if (idx + j < n) rowptr[idx + j] = run; run += v[j]; }
}

// single 128-thread block scan of per-block sums (nb <= 128)
__global__ __launch_bounds__(128) void scan2(int* __restrict__ bsum, int nb) {
  __shared__ int sh[128];
  int tid = threadIdx.x;
  int v = (tid < nb) ? bsum[tid] : 0;
  sh[tid] = v;
  __syncthreads();
  for (int off = 1; off < 128; off <<= 1) {
    int x = (tid >= off) ? sh[tid - off] : 0;
    __syncthreads();
    sh[tid] += x;
    __syncthreads();
  }
  if (tid < nb) bsum[tid] = sh[tid] - v;
}

__global__ void scan3(int* __restrict__ rowptr, int* __restrict__ pos,
                      const int* __restrict__ bsum, int n, int E) {
  int t = blockIdx.x * 256 + threadIdx.x;
  if (t < n) {
    int v = rowptr[t] + bsum[t >> 10];
    rowptr[t] = v;
    pos[t] = v;
  }
  if (t == 0) rowptr[n] = E;
}

__global__ void edge_scatter(const int* __restrict__ src, const int* __restrict__ dst,
                             int* __restrict__ pos, int* __restrict__ csr_src, int E) {
  int e = blockIdx.x * 256 + threadIdx.x;
  if (e >= E) return;
  int idx = atomicAdd(pos + dst[e], 1);
  csr_src[idx] = src[e];
}

// ---------------- fused layer: gather -> MLP (2 GEMMs) ---------------------
// Gather is done straight into MFMA A-fragments: each lane owns the 32-col
// slice (4 x bf16x8) of 2 rows; per edge it issues 4 independent 16B loads
// (2-edge batches -> 8 loads in flight), breaking the serial chain that
// bounded the standalone gather. Eliminates the agg intermediate entirely.

template<bool IN_BF16, bool LAST>
__global__ __launch_bounds__(256) void layer_fused(const void* __restrict__ zin,
    const int* __restrict__ rowptr, const int* __restrict__ csr_src,
    const unsigned short* __restrict__ Wt1, const float* __restrict__ b1v,
    const unsigned short* __restrict__ Wt2, const float* __restrict__ b2v,
    unsigned short* __restrict__ Zb, float* __restrict__ Zf, int M) {
  __shared__ unsigned short hs[4][32][136];
  int lane = threadIdx.x & 63;
  int wid  = threadIdx.x >> 6;
  int row_base = blockIdx.x * 128 + wid * 32;
  int c16 = lane & 15;
  int kq  = lane >> 4;
  int koff = kq * 8;
  const float* zf = (const float*)zin;
  const unsigned short* zb = (const unsigned short*)zin;

  bf16x8 a[2][4];
#pragma unroll
  for (int fr = 0; fr < 2; ++fr) {
    int row = row_base + fr * 16 + c16;
    row = row < M ? row : M - 1;
    float acc[4][8];

    // self term
    if constexpr (IN_BF16) {
      const unsigned short* zr = zb + (size_t)row * D + koff;
#pragma unroll
      for (int kk = 0; kk < 4; ++kk) {
        bf16x8 v = *(const bf16x8*)(zr + kk * 32);
#pragma unroll
        for (int j = 0; j < 8; ++j) acc[kk][j] = bf2f((unsigned short)v[j]);
      }
    } else {
      const float* zr = zf + (size_t)row * D + koff;
#pragma unroll
      for (int kk = 0; kk < 4; ++kk) {
        float4 v0 = *(const float4*)(zr + kk * 32);
        float4 v1 = *(const float4*)(zr + kk * 32 + 4);
        acc[kk][0] = v0.x; acc[kk][1] = v0.y; acc[kk][2] = v0.z; acc[kk][3] = v0.w;
        acc[kk][4] = v1.x; acc[kk][5] = v1.y; acc[kk][6] = v1.z; acc[kk][7] = v1.w;
      }
    }

    int e  = rowptr[row];
    int e1 = rowptr[row + 1];

    if constexpr (IN_BF16) {
      // 2-edge batches: 8 independent 16B loads in flight per lane
      for (; e + 2 <= e1; e += 2) {
        int s0 = csr_src[e];
        int s1 = csr_src[e + 1];
        const unsigned short* p0 = zb + (size_t)s0 * D + koff;
        const unsigned short* p1 = zb + (size_t)s1 * D + koff;
        bf16x8 u0 = *(const bf16x8*)(p0);
        bf16x8 u1 = *(const bf16x8*)(p0 + 32);
        bf16x8 u2 = *(const bf16x8*)(p0 + 64);
        bf16x8 u3 = *(const bf16x8*)(p0 + 96);
        bf16x8 w0 = *(const bf16x8*)(p1);
        bf16x8 w1 = *(const bf16x8*)(p1 + 32);
        bf16x8 w2 = *(const bf16x8*)(p1 + 64);
        bf16x8 w3 = *(const bf16x8*)(p1 + 96);
#pragma unroll
        for (int j = 0; j < 8; ++j) {
          acc[0][j] += bf2f((unsigned short)u0[j]) + bf2f((unsigned short)w0[j]);
          acc[1][j] += bf2f((unsigned short)u1[j]) + bf2f((unsigned short)w1[j]);
          acc[2][j] += bf2f((unsigned short)u2[j]) + bf2f((unsigned short)w2[j]);
          acc[3][j] += bf2f((unsigned short)u3[j]) + bf2f((unsigned short)w3[j]);
        }
      }
      if (e < e1) {
        int s0 = csr_src[e];
        const unsigned short* p0 = zb + (size_t)s0 * D + koff;
        bf16x8 u0 = *(const bf16x8*)(p0);
        bf16x8 u1 = *(const bf16x8*)(p0 + 32);
        bf16x8 u2 = *(const bf16x8*)(p0 + 64);
        bf16x8 u3 = *(const bf16x8*)(p0 + 96);
#pragma unroll
        for (int j = 0; j < 8; ++j) {
          acc[0][j] += bf2f((unsigned short)u0[j]);
          acc[1][j] += bf2f((unsigned short)u1[j]);
          acc[2][j] += bf2f((unsigned short)u2[j]);
          acc[3][j] += bf2f((unsigned short)u3[j]);
        }
      }
    } else {
      // f32 input (layer 0): 8 independent 16B loads in flight per edge
      for (; e < e1; ++e) {
        int s0 = csr_src[e];
        const float* p0 = zf + (size_t)s0 * D + koff;
        float4 v0 = *(const float4*)(p0);
        float4 v1 = *(const float4*)(p0 + 4);
        float4 v2 = *(const float4*)(p0 + 32);
        float4 v3 = *(const float4*)(p0 + 36);
        float4 v4 = *(const float4*)(p0 + 64);
        float4 v5 = *(const float4*)(p0 + 68);
        float4 v6 = *(const float4*)(p0 + 96);
        float4 v7 = *(const float4*)(p0 + 100);
        acc[0][0] += v0.x; acc[0][1] += v0.y; acc[0][2] += v0.z; acc[0][3] += v0.w;
        acc[0][4] += v1.x; acc[0][5] += v1.y; acc[0][6] += v1.z; acc[0][7] += v1.w;
        acc[1][0] += v2.x; acc[1][1] += v2.y; acc[1][2] += v2.z; acc[1][3] += v2.w;
        acc[1][4] += v3.x; acc[1][5] += v3.y; acc[1][6] += v3.z; acc[1][7] += v3.w;
        acc[2][0] += v4.x; acc[2][1] += v4.y; acc[2][2] += v4.z; acc[2][3] += v4.w;
        acc[2][4] += v5.x; acc[2][5] += v5.y; acc[2][6] += v5.z; acc[2][7] += v5.w;
        acc[3][0] += v6.x; acc[3][1] += v6.y; acc[3][2] += v6.z; acc[3][3] += v6.w;
        acc[3][4] += v7.x; acc[3][5] += v7.y; acc[3][6] += v7.z; acc[3][7] += v7.w;
      }
    }

    // convert to bf16 A-fragments (same rounding as old agg bf16 round-trip)
#pragma unroll
    for (int kk = 0; kk < 4; ++kk) {
      bf16x8 t;
#pragma unroll
      for (int j = 0; j < 8; ++j) t[j] = (short)f2bf(acc[kk][j]);
      a[fr][kk] = t;
    }
  }

  // GEMM1 -> LDS
#pragma unroll
  for (int fc = 0; fc < 8; ++fc) {
    f32x4 acc0 = {0.f, 0.f, 0.f, 0.f};
    f32x4 acc1 = {0.f, 0.f, 0.f, 0.f};
    int col = fc * 16 + c16;
#pragma unroll
    for (int kk = 0; kk < 4; ++kk) {
      bf16x8 b = *(const bf16x8*)(Wt1 + (size_t)col * D + kk * 32 + koff);
      acc0 = __builtin_amdgcn_mfma_f32_16x16x32_bf16(a[0][kk], b, acc0, 0, 0, 0);
      acc1 = __builtin_amdgcn_mfma_f32_16x16x32_bf16(a[1][kk], b, acc1, 0, 0, 0);
    }
    float bv = b1v[col];
#pragma unroll
    for (int r = 0; r < 4; ++r) {
      int rl = kq * 4 + r;
      hs[wid][rl][col]      = f2bf(fmaxf(acc0[r] + bv, 0.f));
      hs[wid][rl + 16][col] = f2bf(fmaxf(acc1[r] + bv, 0.f));
    }
  }
  __syncthreads();

  bf16x8 a2[2][4];
#pragma unroll
  for (int fr = 0; fr < 2; ++fr)
#pragma unroll
    for (int kk = 0; kk < 4; ++kk)
      a2[fr][kk] = *(const bf16x8*)&hs[wid][fr * 16 + c16][kk * 32 + koff];

  // GEMM2 -> global
#pragma unroll
  for (int fc = 0; fc < 8; ++fc) {
    f32x4 acc0 = {0.f, 0.f, 0.f, 0.f};
    f32x4 acc1 = {0.f, 0.f, 0.f, 0.f};
    int col = fc * 16 + c16;
#pragma unroll
    for (int kk = 0; kk < 4; ++kk) {
      bf16x8 b = *(const bf16x8*)(Wt2 + (size_t)col * D + kk * 32 + koff);
      acc0 = __builtin_amdgcn_mfma_f32_16x16x32_bf16(a2[0][kk], b, acc0, 0, 0, 0);
      acc1 = __builtin_amdgcn_mfma_f32_16x16x32_bf16(a2[1][kk], b, acc1, 0, 0, 0);
    }
    float bv = b2v[col];
#pragma unroll
    for (int r = 0; r < 4; ++r) {
      int row0 = row_base + kq * 4 + r;
      float v0 = fmaxf(acc0[r] + bv, 0.f);
      if (row0 < M) {
        if constexpr (LAST) Zf[(size_t)row0 * D + col] = v0;
        else                Zb[(size_t)row0 * D + col] = f2bf(v0);
      }
      int row1 = row0 + 16;
      float v1 = fmaxf(acc1[r] + bv, 0.f);
      if (row1 < M) {
        if constexpr (LAST) Zf[(size_t)row1 * D + col] = v1;
        else                Zb[(size_t)row1 * D + col] = f2bf(v1);
      }
    }
  }
}

// ---------------- pooling: sorted batch -> chunked segmented mean ----------

__global__ void pool_zero(float* __restrict__ g, int* __restrict__ counts) {
  int t = blockIdx.x * 256 + threadIdx.x;
  if (t < NG * D) g[t] = 0.f;
  if (t < NG) counts[t] = 0;
}

__global__ __launch_bounds__(128) void pool_accum(const float* __restrict__ z,
    const int* __restrict__ batch, float* __restrict__ g, int* __restrict__ counts, int N) {
  int col = threadIdx.x;
  int r0 = blockIdx.x * PROWS;
  if (r0 >= N) return;
  int r1 = min(r0 + PROWS, N);
  float acc = 0.f;
  int cur = batch[r0];
  int segstart = r0;
  for (int i = r0; i < r1; ++i) {
    int b = batch[i];
    if (b != cur) {
      atomicAdd(g + (size_t)cur * D + col, acc);
      if (col == 0) atomicAdd(counts + cur, i - segstart);
      acc = 0.f; cur = b; segstart = i;
    }
    acc += z[(size_t)i * D + col];
  }
  atomicAdd(g + (size_t)cur * D + col, acc);
  if (col == 0) atomicAdd(counts + cur, r1 - segstart);
}

__global__ void pool_div(float* __restrict__ g, const int* __restrict__ counts) {
  int t = blockIdx.x * 256 + threadIdx.x;
  if (t >= NG * D) return;
  g[t] = g[t] / fmaxf((float)counts[t >> 7], 1.f);
}

extern "C" void kernel_launch(void* const* d_in, const int* in_sizes, int n_in,
                              void* d_out, int out_size, void* d_ws, size_t ws_size,
                              hipStream_t stream) {
  const float* x     = (const float*)d_in[0];
  const int*   ei    = (const int*)d_in[1];
  const int*   batch = (const int*)d_in[2];
  const float* W1    = (const float*)d_in[3];
  const float* b1    = (const float*)d_in[4];
  const float* W2    = (const float*)d_in[5];
  const float* b2    = (const float*)d_in[6];

  const int N = in_sizes[0] / D;       // 100000
  const int E = in_sizes[1] / 2;       // 640000
  const int* src = ei;
  const int* dst = ei + E;

  float* zout = (float*)d_out;
  float* g    = zout + (size_t)N * D;

  // workspace layout
  char* w = (char*)d_ws;
  unsigned short* zb_a    = (unsigned short*)w;    w += (size_t)N * D * 2;
  unsigned short* zb_b    = (unsigned short*)w;    w += (size_t)N * D * 2;
  unsigned short* Wt1     = (unsigned short*)w;    w += 3 * 16384 * 2;
  unsigned short* Wt2     = (unsigned short*)w;    w += 3 * 16384 * 2;
  int*            counts  = (int*)w;               w += NG * 4;
  int*            deg     = (int*)w;               w += (size_t)N * 4;
  int*            rowptr  = (int*)w;               w += (size_t)(N + 4) * 4;
  int*            pos     = (int*)w;               w += (size_t)N * 4;
  int*            bsum    = (int*)w;               w += 128 * 4;
  int*            csr_src = (int*)w;               w += (size_t)E * 4;

  const int nb = (N + 1023) / 1024;   // 98 <= 128

  // weight prep + deg zero (folded)
  int prep_threads = (3 * 128 * 128 > N) ? 3 * 128 * 128 : N;
  prep_w<<<(prep_threads + 255) / 256, 256, 0, stream>>>(W1, W2, Wt1, Wt2, deg, N);

  // CSR build
  hist_deg<<<(E + 255) / 256, 256, 0, stream>>>(dst, deg, E);
  scan1<<<nb, 256, 0, stream>>>(deg, rowptr, bsum, N);
  scan2<<<1, 128, 0, stream>>>(bsum, nb);
  scan3<<<(N + 255) / 256, 256, 0, stream>>>(rowptr, pos, bsum, N, E);
  edge_scatter<<<(E + 255) / 256, 256, 0, stream>>>(src, dst, pos, csr_src, E);

  const int blocks = (N + 127) / 128;

  // fused layers: gather + MLP in one kernel, no agg intermediate
  layer_fused<false, false><<<blocks, 256, 0, stream>>>(x, rowptr, csr_src,
      Wt1, b1, Wt2, b2, zb_a, zout, N);
  layer_fused<true, false><<<blocks, 256, 0, stream>>>(zb_a, rowptr, csr_src,
      Wt1 + 16384, b1 + 128, Wt2 + 16384, b2 + 128, zb_b, zout, N);
  layer_fused<true, true><<<blocks, 256, 0, stream>>>(zb_b, rowptr, csr_src,
      Wt1 + 32768, b1 + 256, Wt2 + 32768, b2 + 256, zb_a, zout, N);

  pool_zero<<<(NG * D + 255) / 256, 256, 0, stream>>>(g, counts);
  pool_accum<<<(N + PROWS - 1) / PROWS, 128, 0, stream>>>(zout, batch, g, counts, N);
  pool_div<<<(NG * D + 255) / 256, 256, 0, stream>>>(g, counts);
}

// Round 2
// 338.205 us; speedup vs baseline: 1.0595x; 1.0595x over previous
//
#include <hip/hip_runtime.h>
#include <hip/hip_bf16.h>

#define D 128
#define NG 128
#define PROWS 128

typedef __attribute__((ext_vector_type(8))) short bf16x8;
typedef __attribute__((ext_vector_type(4))) float f32x4;

__device__ inline unsigned short f2bf(float f) {
  union { float f; unsigned u; } c; c.f = f;
  unsigned u = c.u;
  return (unsigned short)((u + 0x7FFFu + ((u >> 16) & 1u)) >> 16);  // RNE
}
__device__ inline float bf2f(unsigned short b) {
  union { unsigned u; float f; } c; c.u = ((unsigned)b) << 16;
  return c.f;
}

// Transpose + bf16-convert weights: Wt[l][n][k] = bf16(W[l][k][n]).
// Also zeroes deg[] (folded to save a launch).
__global__ void prep_w(const float* __restrict__ W1, const float* __restrict__ W2,
                       unsigned short* __restrict__ Wt1, unsigned short* __restrict__ Wt2,
                       int* __restrict__ deg, int N) {
  int t = blockIdx.x * 256 + threadIdx.x;
  if (t < N) deg[t] = 0;
  if (t >= 3 * 128 * 128) return;
  int l = t >> 14, k = (t >> 7) & 127, n = t & 127;
  int o = (l << 14) + (n << 7) + k;
  Wt1[o] = f2bf(W1[t]);
  Wt2[o] = f2bf(W2[t]);
}

// ---------------- CSR build ------------------------------------------------

__global__ void hist_deg(const int* __restrict__ dst, int* __restrict__ deg, int E) {
  int e = blockIdx.x * 256 + threadIdx.x;
  if (e < E) atomicAdd(deg + dst[e], 1);
}

__global__ __launch_bounds__(256) void scan1(const int* __restrict__ deg,
    int* __restrict__ rowptr, int* __restrict__ bsum, int n) {
  __shared__ int sh[256];
  int tid = threadIdx.x;
  int idx = blockIdx.x * 1024 + tid * 4;
  int v[4], tsum = 0;
#pragma unroll
  for (int j = 0; j < 4; ++j) { v[j] = (idx + j < n) ? deg[idx + j] : 0; tsum += v[j]; }
  sh[tid] = tsum;
  __syncthreads();
  for (int off = 1; off < 256; off <<= 1) {
    int x = (tid >= off) ? sh[tid - off] : 0;
    __syncthreads();
    sh[tid] += x;
    __syncthreads();
  }
  if (tid == 255) bsum[blockIdx.x] = sh[255];
  int run = sh[tid] - tsum;
#pragma unroll
  for (int j = 0; j < 4; ++j) { if (idx + j < n) rowptr[idx + j] = run; run += v[j]; }
}

// single 128-thread block scan of per-block sums (nb <= 128)
__global__ __launch_bounds__(128) void scan2(int* __restrict__ bsum, int nb) {
  __shared__ int sh[128];
  int tid = threadIdx.x;
  int v = (tid < nb) ? bsum[tid] : 0;
  sh[tid] = v;
  __syncthreads();
  for (int off = 1; off < 128; off <<= 1) {
    int x = (tid >= off) ? sh[tid - off] : 0;
    __syncthreads();
    sh[tid] += x;
    __syncthreads();
  }
  if (tid < nb) bsum[tid] = sh[tid] - v;
}

__global__ void scan3(int* __restrict__ rowptr, int* __restrict__ pos,
                      const int* __restrict__ bsum, int n, int E) {
  int t = blockIdx.x * 256 + threadIdx.x;
  if (t < n) {
    int v = rowptr[t] + bsum[t >> 10];
    rowptr[t] = v;
    pos[t] = v;
  }
  if (t == 0) rowptr[n] = E;
}

__global__ void edge_scatter(const int* __restrict__ src, const int* __restrict__ dst,
                             int* __restrict__ pos, int* __restrict__ csr_src, int E) {
  int e = blockIdx.x * 256 + threadIdx.x;
  if (e >= E) return;
  int idx = atomicAdd(pos + dst[e], 1);
  csr_src[idx] = src[e];
}

// ---------------- fused layer: gather (via LDS) -> MLP (2 GEMMs) -----------
// Phase A restores the R0 gather access pattern INSIDE the fused kernel:
// 8 lanes per row (contiguous 256B per neighbor row, uniform degree within
// a group), 8 independent 16B loads in flight per lane. Result rows are
// staged in an LDS tile that each warp then reads as its MFMA A-fragments.
// Groups 8w..8w+7 are exactly warp w's rows, so the tile region is
// warp-private and aliases the hs buffer of the GEMM phase (no LDS growth).

template<bool IN_BF16, bool LAST>
__global__ __launch_bounds__(256) void layer_fused(const void* __restrict__ zin,
    const int* __restrict__ rowptr, const int* __restrict__ csr_src,
    const unsigned short* __restrict__ Wt1, const float* __restrict__ b1v,
    const unsigned short* __restrict__ Wt2, const float* __restrict__ b2v,
    unsigned short* __restrict__ Zb, float* __restrict__ Zf, int M) {
  __shared__ unsigned short lds[128][136];   // agg tile, then hs (aliased)
  int tid = threadIdx.x;
  int base = blockIdx.x * 128;
  const float* zf = (const float*)zin;
  const unsigned short* zb = (const unsigned short*)zin;

  // ---- phase A: gather. 32 groups x 8 lanes; 4 rows per group ----
  int g = tid >> 3;          // 0..31
  int lanei = tid & 7;       // 0..7
  int c = lanei * 16;        // 16 elements (32B bf16 / 64B f32) per lane

#pragma unroll 1
  for (int rr = 0; rr < 4; ++rr) {
    int rl = g * 4 + rr;               // local row 0..127
    int row = base + rl;
    if (row >= M) row = M - 1;         // clamp; stores are guarded later
    float acc[16];

    // self term
    if constexpr (IN_BF16) {
      const unsigned short* p = zb + (size_t)row * D + c;
      bf16x8 v0 = *(const bf16x8*)(p);
      bf16x8 v1 = *(const bf16x8*)(p + 8);
#pragma unroll
      for (int j = 0; j < 8; ++j) {
        acc[j]     = bf2f((unsigned short)v0[j]);
        acc[j + 8] = bf2f((unsigned short)v1[j]);
      }
    } else {
      const float* p = zf + (size_t)row * D + c;
      float4 v0 = *(const float4*)(p);
      float4 v1 = *(const float4*)(p + 4);
      float4 v2 = *(const float4*)(p + 8);
      float4 v3 = *(const float4*)(p + 12);
      acc[0]  = v0.x; acc[1]  = v0.y; acc[2]  = v0.z; acc[3]  = v0.w;
      acc[4]  = v1.x; acc[5]  = v1.y; acc[6]  = v1.z; acc[7]  = v1.w;
      acc[8]  = v2.x; acc[9]  = v2.y; acc[10] = v2.z; acc[11] = v2.w;
      acc[12] = v3.x; acc[13] = v3.y; acc[14] = v3.z; acc[15] = v3.w;
    }

    int e  = rowptr[row];
    int e1 = rowptr[row + 1];

    if constexpr (IN_BF16) {
      // 4-edge batches: 8 independent 16B loads in flight
      for (; e + 4 <= e1; e += 4) {
        int s0 = csr_src[e + 0];
        int s1 = csr_src[e + 1];
        int s2 = csr_src[e + 2];
        int s3 = csr_src[e + 3];
        const unsigned short* p0 = zb + (size_t)s0 * D + c;
        const unsigned short* p1 = zb + (size_t)s1 * D + c;
        const unsigned short* p2 = zb + (size_t)s2 * D + c;
        const unsigned short* p3 = zb + (size_t)s3 * D + c;
        bf16x8 a0 = *(const bf16x8*)(p0), a1 = *(const bf16x8*)(p0 + 8);
        bf16x8 b0 = *(const bf16x8*)(p1), b1 = *(const bf16x8*)(p1 + 8);
        bf16x8 c0 = *(const bf16x8*)(p2), c1 = *(const bf16x8*)(p2 + 8);
        bf16x8 d0 = *(const bf16x8*)(p3), d1 = *(const bf16x8*)(p3 + 8);
#pragma unroll
        for (int j = 0; j < 8; ++j) {
          acc[j]     += (bf2f((unsigned short)a0[j]) + bf2f((unsigned short)b0[j]))
                      + (bf2f((unsigned short)c0[j]) + bf2f((unsigned short)d0[j]));
          acc[j + 8] += (bf2f((unsigned short)a1[j]) + bf2f((unsigned short)b1[j]))
                      + (bf2f((unsigned short)c1[j]) + bf2f((unsigned short)d1[j]));
        }
      }
      if (e + 2 <= e1) {
        int s0 = csr_src[e + 0];
        int s1 = csr_src[e + 1];
        const unsigned short* p0 = zb + (size_t)s0 * D + c;
        const unsigned short* p1 = zb + (size_t)s1 * D + c;
        bf16x8 a0 = *(const bf16x8*)(p0), a1 = *(const bf16x8*)(p0 + 8);
        bf16x8 b0 = *(const bf16x8*)(p1), b1 = *(const bf16x8*)(p1 + 8);
#pragma unroll
        for (int j = 0; j < 8; ++j) {
          acc[j]     += bf2f((unsigned short)a0[j]) + bf2f((unsigned short)b0[j]);
          acc[j + 8] += bf2f((unsigned short)a1[j]) + bf2f((unsigned short)b1[j]);
        }
        e += 2;
      }
      if (e < e1) {
        int s0 = csr_src[e];
        const unsigned short* p0 = zb + (size_t)s0 * D + c;
        bf16x8 a0 = *(const bf16x8*)(p0), a1 = *(const bf16x8*)(p0 + 8);
#pragma unroll
        for (int j = 0; j < 8; ++j) {
          acc[j]     += bf2f((unsigned short)a0[j]);
          acc[j + 8] += bf2f((unsigned short)a1[j]);
        }
      }
    } else {
      // f32: 2-edge batches, 8 independent 16B loads in flight
      for (; e + 2 <= e1; e += 2) {
        int s0 = csr_src[e + 0];
        int s1 = csr_src[e + 1];
        const float* p0 = zf + (size_t)s0 * D + c;
        const float* p1 = zf + (size_t)s1 * D + c;
        float4 u0 = *(const float4*)(p0);
        float4 u1 = *(const float4*)(p0 + 4);
        float4 u2 = *(const float4*)(p0 + 8);
        float4 u3 = *(const float4*)(p0 + 12);
        float4 w0 = *(const float4*)(p1);
        float4 w1 = *(const float4*)(p1 + 4);
        float4 w2 = *(const float4*)(p1 + 8);
        float4 w3 = *(const float4*)(p1 + 12);
        acc[0]  += u0.x + w0.x; acc[1]  += u0.y + w0.y;
        acc[2]  += u0.z + w0.z; acc[3]  += u0.w + w0.w;
        acc[4]  += u1.x + w1.x; acc[5]  += u1.y + w1.y;
        acc[6]  += u1.z + w1.z; acc[7]  += u1.w + w1.w;
        acc[8]  += u2.x + w2.x; acc[9]  += u2.y + w2.y;
        acc[10] += u2.z + w2.z; acc[11] += u2.w + w2.w;
        acc[12] += u3.x + w3.x; acc[13] += u3.y + w3.y;
        acc[14] += u3.z + w3.z; acc[15] += u3.w + w3.w;
      }
      if (e < e1) {
        int s0 = csr_src[e];
        const float* p0 = zf + (size_t)s0 * D + c;
        float4 u0 = *(const float4*)(p0);
        float4 u1 = *(const float4*)(p0 + 4);
        float4 u2 = *(const float4*)(p0 + 8);
        float4 u3 = *(const float4*)(p0 + 12);
        acc[0]  += u0.x; acc[1]  += u0.y; acc[2]  += u0.z; acc[3]  += u0.w;
        acc[4]  += u1.x; acc[5]  += u1.y; acc[6]  += u1.z; acc[7]  += u1.w;
        acc[8]  += u2.x; acc[9]  += u2.y; acc[10] += u2.z; acc[11] += u2.w;
        acc[12] += u3.x; acc[13] += u3.y; acc[14] += u3.z; acc[15] += u3.w;
      }
    }

    // round to bf16 and stage in LDS agg tile
    bf16x8 o0, o1;
#pragma unroll
    for (int j = 0; j < 8; ++j) {
      o0[j] = (short)f2bf(acc[j]);
      o1[j] = (short)f2bf(acc[j + 8]);
    }
    *(bf16x8*)&lds[rl][c]     = o0;
    *(bf16x8*)&lds[rl][c + 8] = o1;
  }
  __syncthreads();

  // ---- phase B: fused MLP ----
  int lane = tid & 63;
  int wid  = tid >> 6;
  int row_base = base + wid * 32;
  int c16 = lane & 15;
  int kq  = lane >> 4;
  int koff = kq * 8;

  bf16x8 a[2][4];
#pragma unroll
  for (int fr = 0; fr < 2; ++fr)
#pragma unroll
    for (int kk = 0; kk < 4; ++kk)
      a[fr][kk] = *(const bf16x8*)&lds[wid * 32 + fr * 16 + c16][kk * 32 + koff];
  __syncthreads();

  // GEMM1 -> LDS (hs region aliases agg tile; warp-private rows)
#pragma unroll
  for (int fc = 0; fc < 8; ++fc) {
    f32x4 acc0 = {0.f, 0.f, 0.f, 0.f};
    f32x4 acc1 = {0.f, 0.f, 0.f, 0.f};
    int col = fc * 16 + c16;
#pragma unroll
    for (int kk = 0; kk < 4; ++kk) {
      bf16x8 b = *(const bf16x8*)(Wt1 + (size_t)col * D + kk * 32 + koff);
      acc0 = __builtin_amdgcn_mfma_f32_16x16x32_bf16(a[0][kk], b, acc0, 0, 0, 0);
      acc1 = __builtin_amdgcn_mfma_f32_16x16x32_bf16(a[1][kk], b, acc1, 0, 0, 0);
    }
    float bv = b1v[col];
#pragma unroll
    for (int r = 0; r < 4; ++r) {
      int rl = kq * 4 + r;
      lds[wid * 32 + rl][col]      = f2bf(fmaxf(acc0[r] + bv, 0.f));
      lds[wid * 32 + rl + 16][col] = f2bf(fmaxf(acc1[r] + bv, 0.f));
    }
  }
  __syncthreads();

  bf16x8 a2[2][4];
#pragma unroll
  for (int fr = 0; fr < 2; ++fr)
#pragma unroll
    for (int kk = 0; kk < 4; ++kk)
      a2[fr][kk] = *(const bf16x8*)&lds[wid * 32 + fr * 16 + c16][kk * 32 + koff];

  // GEMM2 -> global
#pragma unroll
  for (int fc = 0; fc < 8; ++fc) {
    f32x4 acc0 = {0.f, 0.f, 0.f, 0.f};
    f32x4 acc1 = {0.f, 0.f, 0.f, 0.f};
    int col = fc * 16 + c16;
#pragma unroll
    for (int kk = 0; kk < 4; ++kk) {
      bf16x8 b = *(const bf16x8*)(Wt2 + (size_t)col * D + kk * 32 + koff);
      acc0 = __builtin_amdgcn_mfma_f32_16x16x32_bf16(a2[0][kk], b, acc0, 0, 0, 0);
      acc1 = __builtin_amdgcn_mfma_f32_16x16x32_bf16(a2[1][kk], b, acc1, 0, 0, 0);
    }
    float bv = b2v[col];
#pragma unroll
    for (int r = 0; r < 4; ++r) {
      int row0 = row_base + kq * 4 + r;
      float v0 = fmaxf(acc0[r] + bv, 0.f);
      if (row0 < M) {
        if constexpr (LAST) Zf[(size_t)row0 * D + col] = v0;
        else                Zb[(size_t)row0 * D + col] = f2bf(v0);
      }
      int row1 = row0 + 16;
      float v1 = fmaxf(acc1[r] + bv, 0.f);
      if (row1 < M) {
        if constexpr (LAST) Zf[(size_t)row1 * D + col] = v1;
        else                Zb[(size_t)row1 * D + col] = f2bf(v1);
      }
    }
  }
}

// ---------------- pooling: sorted batch -> chunked segmented mean ----------

__global__ void pool_zero(float* __restrict__ g, int* __restrict__ counts) {
  int t = blockIdx.x * 256 + threadIdx.x;
  if (t < NG * D) g[t] = 0.f;
  if (t < NG) counts[t] = 0;
}

__global__ __launch_bounds__(128) void pool_accum(const float* __restrict__ z,
    const int* __restrict__ batch, float* __restrict__ g, int* __restrict__ counts, int N) {
  int col = threadIdx.x;
  int r0 = blockIdx.x * PROWS;
  if (r0 >= N) return;
  int r1 = min(r0 + PROWS, N);
  float acc = 0.f;
  int cur = batch[r0];
  int segstart = r0;
  for (int i = r0; i < r1; ++i) {
    int b = batch[i];
    if (b != cur) {
      atomicAdd(g + (size_t)cur * D + col, acc);
      if (col == 0) atomicAdd(counts + cur, i - segstart);
      acc = 0.f; cur = b; segstart = i;
    }
    acc += z[(size_t)i * D + col];
  }
  atomicAdd(g + (size_t)cur * D + col, acc);
  if (col == 0) atomicAdd(counts + cur, r1 - segstart);
}

__global__ void pool_div(float* __restrict__ g, const int* __restrict__ counts) {
  int t = blockIdx.x * 256 + threadIdx.x;
  if (t >= NG * D) return;
  g[t] = g[t] / fmaxf((float)counts[t >> 7], 1.f);
}

extern "C" void kernel_launch(void* const* d_in, const int* in_sizes, int n_in,
                              void* d_out, int out_size, void* d_ws, size_t ws_size,
                              hipStream_t stream) {
  const float* x     = (const float*)d_in[0];
  const int*   ei    = (const int*)d_in[1];
  const int*   batch = (const int*)d_in[2];
  const float* W1    = (const float*)d_in[3];
  const float* b1    = (const float*)d_in[4];
  const float* W2    = (const float*)d_in[5];
  const float* b2    = (const float*)d_in[6];

  const int N = in_sizes[0] / D;       // 100000
  const int E = in_sizes[1] / 2;       // 640000
  const int* src = ei;
  const int* dst = ei + E;

  float* zout = (float*)d_out;
  float* g    = zout + (size_t)N * D;

  // workspace layout
  char* w = (char*)d_ws;
  unsigned short* zb_a    = (unsigned short*)w;    w += (size_t)N * D * 2;
  unsigned short* zb_b    = (unsigned short*)w;    w += (size_t)N * D * 2;
  unsigned short* Wt1     = (unsigned short*)w;    w += 3 * 16384 * 2;
  unsigned short* Wt2     = (unsigned short*)w;    w += 3 * 16384 * 2;
  int*            counts  = (int*)w;               w += NG * 4;
  int*            deg     = (int*)w;               w += (size_t)N * 4;
  int*            rowptr  = (int*)w;               w += (size_t)(N + 4) * 4;
  int*            pos     = (int*)w;               w += (size_t)N * 4;
  int*            bsum    = (int*)w;               w += 128 * 4;
  int*            csr_src = (int*)w;               w += (size_t)E * 4;

  const int nb = (N + 1023) / 1024;   // 98 <= 128

  // weight prep + deg zero (folded)
  int prep_threads = (3 * 128 * 128 > N) ? 3 * 128 * 128 : N;
  prep_w<<<(prep_threads + 255) / 256, 256, 0, stream>>>(W1, W2, Wt1, Wt2, deg, N);

  // CSR build
  hist_deg<<<(E + 255) / 256, 256, 0, stream>>>(dst, deg, E);
  scan1<<<nb, 256, 0, stream>>>(deg, rowptr, bsum, N);
  scan2<<<1, 128, 0, stream>>>(bsum, nb);
  scan3<<<(N + 255) / 256, 256, 0, stream>>>(rowptr, pos, bsum, N, E);
  edge_scatter<<<(E + 255) / 256, 256, 0, stream>>>(src, dst, pos, csr_src, E);

  const int blocks = (N + 127) / 128;

  // fused layers: gather + MLP in one kernel, agg staged in LDS
  layer_fused<false, false><<<blocks, 256, 0, stream>>>(x, rowptr, csr_src,
      Wt1, b1, Wt2, b2, zb_a, zout, N);
  layer_fused<true, false><<<blocks, 256, 0, stream>>>(zb_a, rowptr, csr_src,
      Wt1 + 16384, b1 + 128, Wt2 + 16384, b2 + 128, zb_b, zout, N);
  layer_fused<true, true><<<blocks, 256, 0, stream>>>(zb_b, rowptr, csr_src,
      Wt1 + 32768, b1 + 256, Wt2 + 32768, b2 + 256, zb_a, zout, N);

  pool_zero<<<(NG * D + 255) / 256, 256, 0, stream>>>(g, counts);
  pool_accum<<<(N + PROWS - 1) / PROWS, 128, 0, stream>>>(zout, batch, g, counts, N);
  pool_div<<<(NG * D + 255) / 256, 256, 0, stream>>>(g, counts);
}